// Round 5
// baseline (44.640 us; speedup 1.0000x reference)
//
#include <hip/hip_runtime.h>

#define BATCH 999
#define HID 1024
#define SEQ 160

#define BB 64                         // batches per block (4 waves x 16)
#define WB 16                         // batches per wave
#define NBB 16                        // 16 * 64 = 1024 >= 999
#define KS 4                          // k-split
#define KPER (HID / KS)               // 256 k per block (= 64 lanes x float4)
#define HS 16                         // h-split
#define HPER (HID / HS)               // 64 h per block
#define NTILE (KS * HS)               // 64 hk-tiles per b-group

// Cross-block staging (device-coherent access only; zero-init not required:
// every slot is written each launch before it is read).
__device__ float gpart[NTILE][NBB][BB];     // 256 KB
__device__ unsigned gcnt[NBB];              // wraps mod 64 each launch: no reset

__global__ __launch_bounds__(256, 4)        // force <=128 VGPR -> 4 waves/SIMD
void dots_kernel(const float* __restrict__ Cg, const float* __restrict__ Rg,
                 const float* __restrict__ Mg, float* __restrict__ out)
{
    __shared__ float sC[HPER][BB];    // 16 KB, C transposed: sC[h][b]
    __shared__ float sRed[4][BB];     // 1 KB, tail reduction
    __shared__ int sdone;

    const int tid  = threadIdx.x;
    const int lane = tid & 63;
    const int w    = tid >> 6;        // wave id 0..3 -> owns 16 batches

    // XCD-aware bijective decode: per-XCD working set
    // M 512KB + R-quarter 1MB + C 2MB  ~= 3.5MB < 4MB L2
    const int L    = blockIdx.x;      // 0..1023
    const int xcd  = L & 7;
    const int slot = L >> 3;          // 0..127
    const int tile = xcd * 8 + (slot & 7);   // 0..63
    const int by   = slot >> 3;       // 0..15
    const int kx   = tile >> 4;       // 0..3
    const int hz   = tile & 15;       // 0..15
    const int b0   = by * BB;
    const int k0   = kx * KPER;
    const int h0   = hz * HPER;

    // ---- stage C slice once: sC[h][b] = C[b0+b][last, h0+h] ----
    {
        const int b  = tid & 63;
        const int hq = tid >> 6;      // 0..3, 16 h-values each
        const int gb = b0 + b;
        float4 v[4];
        #pragma unroll
        for (int q = 0; q < 4; ++q) v[q] = make_float4(0.f, 0.f, 0.f, 0.f);
        if (gb < BATCH) {
            const float* cp = Cg + ((size_t)gb * SEQ + (SEQ - 1)) * HID + h0 + hq * 16;
            #pragma unroll
            for (int q = 0; q < 4; ++q) v[q] = *(const float4*)(cp + 4 * q);
        }
        // bank = b&31 -> 2-way wave64 aliasing = free
        #pragma unroll
        for (int q = 0; q < 4; ++q) {
            sC[hq * 16 + q * 4 + 0][b] = v[q].x;
            sC[hq * 16 + q * 4 + 1][b] = v[q].y;
            sC[hq * 16 + q * 4 + 2][b] = v[q].z;
            sC[hq * 16 + q * 4 + 3][b] = v[q].w;
        }
    }
    __syncthreads();

    float4 acc[WB];   // 16 batches x 4 k-floats (k = k0 + lane*4 + 0..3)
    #pragma unroll
    for (int i = 0; i < WB; ++i) acc[i] = make_float4(0.f, 0.f, 0.f, 0.f);

    // M rows straight from global (L1/L2-resident, coalesced 16B/lane),
    // two-row register prefetch, NO barriers, NO LDS for M.
    const float* mbase = Mg + (size_t)h0 * HID + k0 + (lane << 2);

    auto fmah = [&](int h, float4 m) {
        const float* crow = &sC[h][w << 4];
        const float4 c0 = *(const float4*)(crow);       // wave-uniform broadcasts
        const float4 c1 = *(const float4*)(crow + 4);
        const float4 c2 = *(const float4*)(crow + 8);
        const float4 c3 = *(const float4*)(crow + 12);
        const float cs[WB] = {c0.x, c0.y, c0.z, c0.w, c1.x, c1.y, c1.z, c1.w,
                              c2.x, c2.y, c2.z, c2.w, c3.x, c3.y, c3.z, c3.w};
        #pragma unroll
        for (int i = 0; i < WB; ++i) {
            acc[i].x += cs[i] * m.x; acc[i].y += cs[i] * m.y;
            acc[i].z += cs[i] * m.z; acc[i].w += cs[i] * m.w;
        }
    };

    float4 m0 = *(const float4*)(mbase);
    float4 m1 = *(const float4*)(mbase + HID);

    for (int h = 0; h < HPER - 2; h += 2) {
        const float* nb = mbase + (size_t)(h + 2) * HID;
        float4 n0 = *(const float4*)(nb);
        float4 n1 = *(const float4*)(nb + HID);
        fmah(h, m0);
        fmah(h + 1, m1);
        m0 = n0; m1 = n1;
    }
    fmah(HPER - 2, m0);
    fmah(HPER - 1, m1);

    // ---- epilogue: dot with R row-slice, butterfly, coherent partial store ----
    #pragma unroll
    for (int i = 0; i < WB; ++i) {
        const int gb = b0 + w * WB + i;
        float p = 0.f;
        if (gb < BATCH) {
            const float4 r0 = *(const float4*)(
                Rg + ((size_t)gb * SEQ + (SEQ - 1)) * HID + k0 + (lane << 2));
            p = acc[i].x * r0.x + acc[i].y * r0.y + acc[i].z * r0.z + acc[i].w * r0.w;
        }
        #pragma unroll
        for (int m = 1; m < 64; m <<= 1) p += __shfl_xor(p, m, 64);
        if (lane == 0)
            __hip_atomic_store(&gpart[tile][by][w * WB + i], p,
                               __ATOMIC_RELAXED, __HIP_MEMORY_SCOPE_AGENT);
    }

    // ---- completion protocol: drain stores to coherence point -> counter ----
    asm volatile("s_waitcnt vmcnt(0)" ::: "memory");
    __syncthreads();
    if (tid == 0) {
        unsigned old = __hip_atomic_fetch_add(&gcnt[by], 1u,
                                              __ATOMIC_RELAXED, __HIP_MEMORY_SCOPE_AGENT);
        sdone = ((old & (NTILE - 1)) == (NTILE - 1));
    }
    __syncthreads();

    // ---- fused tail: last-arrival block reduces 64 partials + sigmoid ----
    if (sdone) {
        const int b = tid & 63;
        const int q = tid >> 6;       // 0..3 -> 16 tiles each
        float s = 0.f;
        #pragma unroll
        for (int t = 0; t < 16; ++t)
            s += __hip_atomic_load(&gpart[q * 16 + t][by][b],
                                   __ATOMIC_RELAXED, __HIP_MEMORY_SCOPE_AGENT);
        sRed[q][b] = s;
        __syncthreads();
        if (tid < BB) {
            const int gb = b0 + tid;
            if (gb < BATCH) {
                float d = sRed[0][tid] + sRed[1][tid] + sRed[2][tid] + sRed[3][tid];
                out[gb] = 1.f / (1.f + __expf(-d));
            }
        }
    }
}

extern "C" void kernel_launch(void* const* d_in, const int* in_sizes, int n_in,
                              void* d_out, int out_size, void* d_ws, size_t ws_size,
                              hipStream_t stream) {
    const float* ctx = (const float*)d_in[0];
    const float* rsp = (const float*)d_in[1];
    const float* M   = (const float*)d_in[2];
    float* out = (float*)d_out;
    (void)d_ws; (void)ws_size;

    dim3 grid(NBB * NTILE);   // 1024 blocks = exactly 4/CU, XCD-aware decode
    dots_kernel<<<grid, 256, 0, stream>>>(ctx, rsp, M, out);
}

// Round 6
// 41.768 us; speedup vs baseline: 1.0688x; 1.0688x over previous
//
#include <hip/hip_runtime.h>

#define BATCH 999
#define HID 1024
#define SEQ 160

#define BB 64                         // batches per block (4 waves x 16)
#define WB 16                         // batches per wave
#define NBB 16                        // 16 * 64 = 1024 >= 999
#define KS 2                          // k-split
#define KPER (HID / KS)               // 512 k per block
#define HS 16                         // h-split
#define HPER (HID / HS)               // 64 h per block
#define NTILE (KS * HS)               // 32 hk-tiles per b-group

// Cross-block staging (device-coherent access only; zero-init not required:
// every slot is written each launch before it is read).
__device__ float gpart[NTILE][NBB][BB];     // 131 KB
__device__ unsigned gcnt[NBB];              // wraps mod 32 each launch: no reset

__global__ __launch_bounds__(256, 2)
void dots_kernel(const float* __restrict__ Cg, const float* __restrict__ Rg,
                 const float* __restrict__ Mg, float* __restrict__ out)
{
    __shared__ float sC[HPER][BB];    // 16 KB, C transposed: sC[h][b]
    __shared__ float sRed[4][BB];     // 1 KB, tail reduction
    __shared__ int sdone;

    const int tid  = threadIdx.x;
    const int lane = tid & 63;
    const int w    = tid >> 6;        // wave id 0..3 -> owns 16 batches

    // XCD-aware bijective decode: per-XCD working set ~3.5 MB < 4 MB L2
    const int L    = blockIdx.x;      // 0..511
    const int xcd  = L & 7;
    const int slot = L >> 3;          // 0..63
    const int tile = xcd * 4 + (slot & 3);   // 0..31
    const int by   = slot >> 2;       // 0..15
    const int kx   = tile >> 4;       // 0..1
    const int hz   = tile & 15;       // 0..15
    const int b0   = by * BB;
    const int k0   = kx * KPER;
    const int h0   = hz * HPER;

    // ---- stage C slice once: sC[h][b] = C[b0+b][last, h0+h] ----
    {
        const int b  = tid & 63;
        const int hq = tid >> 6;      // 0..3, 16 h-values each
        const int gb = b0 + b;
        float4 v[4];
        #pragma unroll
        for (int q = 0; q < 4; ++q) v[q] = make_float4(0.f, 0.f, 0.f, 0.f);
        if (gb < BATCH) {
            const float* cp = Cg + ((size_t)gb * SEQ + (SEQ - 1)) * HID + h0 + hq * 16;
            #pragma unroll
            for (int q = 0; q < 4; ++q) v[q] = *(const float4*)(cp + 4 * q);
        }
        // bank = b&31 -> 2-way wave64 aliasing = free
        #pragma unroll
        for (int q = 0; q < 4; ++q) {
            sC[hq * 16 + q * 4 + 0][b] = v[q].x;
            sC[hq * 16 + q * 4 + 1][b] = v[q].y;
            sC[hq * 16 + q * 4 + 2][b] = v[q].z;
            sC[hq * 16 + q * 4 + 3][b] = v[q].w;
        }
    }
    __syncthreads();

    float4 acc[WB][2]; // 16 batches x 8 k-floats
    #pragma unroll
    for (int i = 0; i < WB; ++i) {
        acc[i][0] = make_float4(0.f, 0.f, 0.f, 0.f);
        acc[i][1] = make_float4(0.f, 0.f, 0.f, 0.f);
    }

    // M rows straight from global (L1/L2-resident, coalesced 16B/lane),
    // 2-row register prefetch. C broadcasts double-buffered in registers:
    // the ds_read for rows h+2/h+3 issues BEFORE the FMAs of rows h/h+1,
    // so the lgkmcnt wait sits behind 256 FMA-cycles. NO barriers.
    const float* mbase = Mg + (size_t)h0 * HID + k0 + (lane << 2);

    auto loadC = [&](int h, float4* cq) {
        const float* crow = &sC[h][w << 4];
        cq[0] = *(const float4*)(crow);
        cq[1] = *(const float4*)(crow + 4);
        cq[2] = *(const float4*)(crow + 8);
        cq[3] = *(const float4*)(crow + 12);
    };

    auto fmah = [&](const float4* cq, float4 ma, float4 mb) {
        const float cs[WB] = {cq[0].x, cq[0].y, cq[0].z, cq[0].w,
                              cq[1].x, cq[1].y, cq[1].z, cq[1].w,
                              cq[2].x, cq[2].y, cq[2].z, cq[2].w,
                              cq[3].x, cq[3].y, cq[3].z, cq[3].w};
        #pragma unroll
        for (int i = 0; i < WB; ++i) {
            acc[i][0].x += cs[i] * ma.x; acc[i][0].y += cs[i] * ma.y;
            acc[i][0].z += cs[i] * ma.z; acc[i][0].w += cs[i] * ma.w;
            acc[i][1].x += cs[i] * mb.x; acc[i][1].y += cs[i] * mb.y;
            acc[i][1].z += cs[i] * mb.z; acc[i][1].w += cs[i] * mb.w;
        }
    };

    float4 m0a = *(const float4*)(mbase);
    float4 m0b = *(const float4*)(mbase + 256);
    float4 m1a = *(const float4*)(mbase + HID);
    float4 m1b = *(const float4*)(mbase + HID + 256);
    float4 csA[4], csB[4], csN0[4], csN1[4];
    loadC(0, csA);
    loadC(1, csB);

    for (int h = 0; h < HPER - 2; h += 2) {
        const float* nb = mbase + (size_t)(h + 2) * HID;
        float4 n0a = *(const float4*)(nb);
        float4 n0b = *(const float4*)(nb + 256);
        float4 n1a = *(const float4*)(nb + HID);
        float4 n1b = *(const float4*)(nb + HID + 256);
        loadC(h + 2, csN0);       // issue LDS broadcasts for next row pair
        loadC(h + 3, csN1);
        fmah(csA, m0a, m0b);      // consume previously-loaded bank
        fmah(csB, m1a, m1b);
        m0a = n0a; m0b = n0b; m1a = n1a; m1b = n1b;
        #pragma unroll
        for (int q = 0; q < 4; ++q) { csA[q] = csN0[q]; csB[q] = csN1[q]; }
    }
    fmah(csA, m0a, m0b);
    fmah(csB, m1a, m1b);

    // ---- epilogue: dot with R row-slice, butterfly, coherent partial store ----
    #pragma unroll
    for (int i = 0; i < WB; ++i) {
        const int gb = b0 + w * WB + i;
        float p = 0.f;
        if (gb < BATCH) {
            const float* rp = Rg + ((size_t)gb * SEQ + (SEQ - 1)) * HID + k0 + (lane << 2);
            const float4 r0 = *(const float4*)(rp);
            const float4 r1 = *(const float4*)(rp + 256);
            p = acc[i][0].x * r0.x + acc[i][0].y * r0.y + acc[i][0].z * r0.z + acc[i][0].w * r0.w
              + acc[i][1].x * r1.x + acc[i][1].y * r1.y + acc[i][1].z * r1.z + acc[i][1].w * r1.w;
        }
        #pragma unroll
        for (int m = 1; m < 64; m <<= 1) p += __shfl_xor(p, m, 64);
        if (lane == 0)
            __hip_atomic_store(&gpart[tile][by][w * WB + i], p,
                               __ATOMIC_RELAXED, __HIP_MEMORY_SCOPE_AGENT);
    }

    // ---- completion protocol: drain stores to coherence point -> counter ----
    asm volatile("s_waitcnt vmcnt(0)" ::: "memory");
    __syncthreads();
    if (tid == 0) {
        unsigned old = __hip_atomic_fetch_add(&gcnt[by], 1u,
                                              __ATOMIC_RELAXED, __HIP_MEMORY_SCOPE_AGENT);
        sdone = ((old & (NTILE - 1)) == (NTILE - 1));
    }
    __syncthreads();

    // ---- fused tail: last-arrival block reduces 32 partials + sigmoid ----
    if (sdone) {
        const int b = tid & 63;
        const int q = tid >> 6;       // 0..3 -> 8 tiles each
        float s = 0.f;
        #pragma unroll
        for (int t = 0; t < 8; ++t)
            s += __hip_atomic_load(&gpart[q * 8 + t][by][b],
                                   __ATOMIC_RELAXED, __HIP_MEMORY_SCOPE_AGENT);
        sRed[q][b] = s;
        __syncthreads();
        if (tid < BB) {
            const int gb = b0 + tid;
            if (gb < BATCH) {
                float d = sRed[0][tid] + sRed[1][tid] + sRed[2][tid] + sRed[3][tid];
                out[gb] = 1.f / (1.f + __expf(-d));
            }
        }
    }
}

extern "C" void kernel_launch(void* const* d_in, const int* in_sizes, int n_in,
                              void* d_out, int out_size, void* d_ws, size_t ws_size,
                              hipStream_t stream) {
    const float* ctx = (const float*)d_in[0];
    const float* rsp = (const float*)d_in[1];
    const float* M   = (const float*)d_in[2];
    float* out = (float*)d_out;
    (void)d_ws; (void)ws_size;

    dim3 grid(NBB * NTILE);   // 512 blocks, 1-D XCD-aware decode, 2/CU
    dots_kernel<<<grid, 256, 0, stream>>>(ctx, rsp, M, out);
}